// Round 2
// baseline (2397.534 us; speedup 1.0000x reference)
//
#include <hip/hip_runtime.h>
#include <hip/hip_cooperative_groups.h>
#include <stdint.h>

namespace cg = cooperative_groups;

namespace {

constexpr int B = 4, C = 128, H = 256, W = 256;
constexpr int V = H * W;              // 65536
constexpr int E = 163072;             // 32640+32512+32640+32512+32768
constexpr long long CHW = (long long)C * V;
constexpr int ROUNDS = 17;

// Edge enumeration must match reference concat order exactly:
// [L-vert, L-horiz, R-vert, R-horiz, cross]
__device__ __forceinline__ void edge_uv(int e, int& u, int& v) {
  if (e < 32640) {                       // L vertical: h in 0..254, w in 0..127
    int h = e >> 7, w = e & 127;
    u = (h << 8) + w; v = u + 256;
  } else if (e < 65152) {                // L horizontal: h in 0..255, w in 0..126
    int k = e - 32640; int h = k / 127, w = k - h * 127;
    u = (h << 8) + w; v = u + 1;
  } else if (e < 97792) {                // R vertical
    int k = e - 65152; int h = k >> 7, w = k & 127;
    u = (h << 8) + 128 + w; v = u + 256;
  } else if (e < 130304) {               // R horizontal
    int k = e - 97792; int h = k / 127, w = k - h * 127;
    u = (h << 8) + 128 + w; v = u + 1;
  } else {                               // cross: L[h][w] -- R[h][w]
    int k = e - 130304; int h = k >> 7, w = k & 127;
    u = (h << 8) + w; v = u + 128;
  }
}

// Chase to the effective root: self-loop, or min-id member of a 2-cycle
// (identical to the reference's cyc-break: (p[p]==id) & (id<p) -> root=id).
__device__ __forceinline__ int find_root(const int* __restrict__ par, int v) {
  int cur = v;
  for (int g = 0; g < 70000; ++g) {
    int p = par[cur];
    if (p == cur) break;
    int gp = par[p];
    if (gp == cur) { cur = cur < p ? cur : p; break; }
    cur = p;
  }
  return cur;
}

// Pass 1: per-pixel squared norm (fp64 accumulate) + parent/minE init.
__global__ void k_norm_init(const float* __restrict__ x, double* __restrict__ n2,
                            int* __restrict__ parent, unsigned long long* __restrict__ minE) {
  int idx = blockIdx.x * blockDim.x + threadIdx.x;   // exact B*V grid
  int b = idx >> 16, p = idx & (V - 1);
  const float* xb = x + (long long)b * CHW + p;
  double acc = 0.0;
#pragma unroll 8
  for (int c = 0; c < C; ++c) {
    double t = (double)xb[(long long)c * V];
    acc = fma(t, t, acc);
  }
  n2[idx] = acc;
  parent[idx] = p;
  minE[idx] = ~0ULL;
}

// Pass 2: per-edge cosine (fp64 dot), round once to fp32, pack sortable key.
__global__ void k_weight(const float* __restrict__ x, const double* __restrict__ n2,
                         unsigned long long* __restrict__ wkey) {
  int idx = blockIdx.x * blockDim.x + threadIdx.x;   // exact B*E grid
  int b = idx / E, e = idx - b * E;
  int u, v; edge_uv(e, u, v);
  const float* xb = x + (long long)b * CHW;
  double dot = 0.0;
#pragma unroll 4
  for (int c = 0; c < C; ++c) {
    long long off = (long long)c * V;
    dot = fma((double)xb[off + u], (double)xb[off + v], dot);
  }
  double denom = fmax(sqrt(n2[(b << 16) + u]) * sqrt(n2[(b << 16) + v]), 1e-8);
  float w = (float)(dot / denom);
  unsigned int bits = __float_as_uint(w);
  if (w == 0.0f) bits = 0u;                          // collapse -0.0 to +0.0
  // order-preserving map fp32 -> uint32
  unsigned int mapped = bits ^ (((int)bits < 0) ? 0xFFFFFFFFu : 0x80000000u);
  wkey[idx] = ((unsigned long long)mapped << 32) | (unsigned int)e;
}

// All 17 Boruvka rounds in ONE cooperative kernel: 2 grid barriers per round
// + device-side early exit once no cross-component edge remains.
__global__ __launch_bounds__(256, 4)
void k_mst(int* __restrict__ parent, int* __restrict__ root,
           unsigned long long* __restrict__ minE,
           const unsigned long long* __restrict__ wkey,
           float* __restrict__ out, int* __restrict__ flags) {
  cg::grid_group grid = cg::this_grid();
  const int T = gridDim.x * blockDim.x;              // 262144
  const int tid = blockIdx.x * blockDim.x + threadIdx.x;

  for (int r = 0; r < ROUNDS; ++r) {
    // Phase B: per-edge. parent/minE stable (written pre-barrier last round).
    int any = 0;
    for (int idx = tid; idx < B * E; idx += T) {
      int b = idx / E, e = idx - b * E;
      int u, v; edge_uv(e, u, v);
      const int* par = parent + (b << 16);
      int* rt = root + (b << 16);
      int ru = find_root(par, u);
      int rv = find_root(par, v);
      rt[u] = ru;                                    // duplicate stores: same value
      rt[v] = rv;
      if (ru != rv) {
        any = 1;
        unsigned long long k = wkey[idx];
        unsigned long long* mb = minE + (b << 16);
        atomicMin(mb + ru, k);
        atomicMin(mb + rv, k);
      }
    }
    unsigned long long m = __ballot(any);
    if (m && (threadIdx.x & 63) == 0) atomicOr(flags + r, 1);
    grid.sync();

    if (__hip_atomic_load(flags + r, __ATOMIC_RELAXED, __HIP_MEMORY_SCOPE_AGENT) == 0)
      break;                                         // uniform: all threads agree

    // Phase C: per-vertex. root/minE stable; each thread writes only parent[idx].
    {
      int idx = tid;                                 // exactly B*V threads
      int b = idx >> 16, v = idx & (V - 1);
      int rr = root[idx];
      int np = rr;                                   // compression (non-roots)
      if (rr == v) {
        unsigned long long k = minE[idx];
        if (k != ~0ULL) {
          int e = (int)(k & 0xFFFFFFFFu);
          int eu, ev; edge_uv(e, eu, ev);
          const int* rt = root + (b << 16);
          int ru = rt[eu], rv2 = rt[ev];
          out[b * E + e] = 1.0f;                     // winner (idempotent dup)
          np = (v == ru) ? rv2 : ru;                 // hook to other component
        }
      }
      parent[idx] = np;
      minE[idx] = ~0ULL;                             // re-init for next round
    }
    grid.sync();
  }
}

} // namespace

extern "C" void kernel_launch(void* const* d_in, const int* in_sizes, int n_in,
                              void* d_out, int out_size, void* d_ws, size_t ws_size,
                              hipStream_t stream) {
  const float* x = (const float*)d_in[0];
  float* out = (float*)d_out;

  char* ws = (char*)d_ws;
  size_t off = 0;
  auto alloc = [&](size_t bytes) {
    void* p = (void*)(ws + off);
    off += (bytes + 255) & ~(size_t)255;
    return p;
  };
  int* parent = (int*)alloc((size_t)B * V * sizeof(int));                      // 1 MB
  int* root   = (int*)alloc((size_t)B * V * sizeof(int));                      // 1 MB
  unsigned long long* minE = (unsigned long long*)alloc((size_t)B * V * 8);    // 2 MB
  double* n2  = (double*)alloc((size_t)B * V * sizeof(double));                // 2 MB
  unsigned long long* wkey = (unsigned long long*)alloc((size_t)B * E * 8);    // ~5 MB
  int* flags  = (int*)alloc(ROUNDS * sizeof(int));

  hipMemsetAsync(d_out, 0, (size_t)B * E * sizeof(float), stream);
  hipMemsetAsync(flags, 0, ROUNDS * sizeof(int), stream);

  k_norm_init<<<(B * V) / 256, 256, 0, stream>>>(x, n2, parent, minE);
  k_weight<<<(B * E) / 256, 256, 0, stream>>>(x, n2, wkey);

  void* args[] = {&parent, &root, &minE, &wkey, &out, &flags};
  hipLaunchCooperativeKernel((void*)k_mst, dim3(1024), dim3(256), args, 0, stream);
}

// Round 3
// 410.641 us; speedup vs baseline: 5.8385x; 5.8385x over previous
//
#include <hip/hip_runtime.h>
#include <stdint.h>

namespace {

constexpr int B = 4, C = 128, H = 256, W = 256;
constexpr int V = H * W;              // 65536
constexpr int E = 163072;             // 32640+32512+32640+32512+32768
constexpr long long CHW = (long long)C * V;
constexpr int ROUNDS = 17;

// Edge enumeration must match reference concat order exactly:
// [L-vert, L-horiz, R-vert, R-horiz, cross]
__device__ __forceinline__ void edge_uv(int e, int& u, int& v) {
  if (e < 32640) {                       // L vertical: h in 0..254, w in 0..127
    int h = e >> 7, w = e & 127;
    u = (h << 8) + w; v = u + 256;
  } else if (e < 65152) {                // L horizontal: h in 0..255, w in 0..126
    int k = e - 32640; int h = k / 127, w = k - h * 127;
    u = (h << 8) + w; v = u + 1;
  } else if (e < 97792) {                // R vertical
    int k = e - 65152; int h = k >> 7, w = k & 127;
    u = (h << 8) + 128 + w; v = u + 256;
  } else if (e < 130304) {               // R horizontal
    int k = e - 97792; int h = k / 127, w = k - h * 127;
    u = (h << 8) + 128 + w; v = u + 1;
  } else {                               // cross: L[h][w] -- R[h][w]
    int k = e - 130304; int h = k >> 7, w = k & 127;
    u = (h << 8) + w; v = u + 128;
  }
}

// Chase to the effective root: self-loop, or min-id member of a 2-cycle
// (identical to the reference's cyc-break: (p[p]==id) & (id<p) -> root=id).
// Verified exact (absmax 0.0) in rounds 1 and 2.
__device__ __forceinline__ int find_root(const int* __restrict__ par, int v) {
  int cur = v;
  for (int g = 0; g < 70000; ++g) {
    int p = par[cur];
    if (p == cur) break;
    int gp = par[p];
    if (gp == cur) { cur = cur < p ? cur : p; break; }
    cur = p;
  }
  return cur;
}

// Pass 1: per-pixel squared norm (fp64 accumulate) + parent/minE/flags init.
__global__ void k_norm_init(const float* __restrict__ x, double* __restrict__ n2,
                            int* __restrict__ parent, unsigned long long* __restrict__ minE,
                            int* __restrict__ flags) {
  int idx = blockIdx.x * blockDim.x + threadIdx.x;   // exact B*V grid
  int b = idx >> 16, p = idx & (V - 1);
  const float* xb = x + (long long)b * CHW + p;
  double acc = 0.0;
#pragma unroll 8
  for (int c = 0; c < C; ++c) {
    double t = (double)xb[(long long)c * V];
    acc = fma(t, t, acc);
  }
  n2[idx] = acc;
  parent[idx] = p;
  minE[idx] = ~0ULL;
  if (idx < ROUNDS) flags[idx] = 0;
}

// Pass 2: per-edge cosine (fp64 dot), round once to fp32, pack sortable key.
// Also zeroes the output mask (runs before any winner marking).
__global__ void k_weight(const float* __restrict__ x, const double* __restrict__ n2,
                         unsigned long long* __restrict__ wkey, float* __restrict__ out) {
  int idx = blockIdx.x * blockDim.x + threadIdx.x;   // exact B*E grid
  int b = idx / E, e = idx - b * E;
  int u, v; edge_uv(e, u, v);
  const float* xb = x + (long long)b * CHW;
  double dot = 0.0;
#pragma unroll 4
  for (int c = 0; c < C; ++c) {
    long long off = (long long)c * V;
    dot = fma((double)xb[off + u], (double)xb[off + v], dot);
  }
  double denom = fmax(sqrt(n2[(b << 16) + u]) * sqrt(n2[(b << 16) + v]), 1e-8);
  float w = (float)(dot / denom);
  unsigned int bits = __float_as_uint(w);
  if (w == 0.0f) bits = 0u;                          // collapse -0.0 to +0.0
  // order-preserving map fp32 -> uint32
  unsigned int mapped = bits ^ (((int)bits < 0) ? 0xFFFFFFFFu : 0x80000000u);
  wkey[idx] = ((unsigned long long)mapped << 32) | (unsigned int)e;
  out[idx] = 0.0f;
}

// Round phase 1 (per edge): chase both endpoint roots (inline 2-cycle
// resolution), publish them, atomicMin the packed (weight,edge) key per
// component, raise this round's "still merging" flag.
__global__ void k_edgemin(const int* __restrict__ parent, int* __restrict__ root,
                          const unsigned long long* __restrict__ wkey,
                          unsigned long long* __restrict__ minE,
                          int* __restrict__ flags, int r) {
  if (r > 0 && __hip_atomic_load(flags + r - 1, __ATOMIC_RELAXED,
                                 __HIP_MEMORY_SCOPE_AGENT) == 0)
    return;                                          // converged: no-op round
  __shared__ int bflag;
  if (threadIdx.x == 0) bflag = 0;
  __syncthreads();

  int idx = blockIdx.x * blockDim.x + threadIdx.x;   // exact B*E grid
  int b = idx / E, e = idx - b * E;
  int u, v; edge_uv(e, u, v);
  const int* par = parent + (b << 16);
  int* rt = root + (b << 16);
  int ru = find_root(par, u);
  int rv = find_root(par, v);
  rt[u] = ru;                                        // duplicate stores: same value
  rt[v] = rv;
  if (ru != rv) {
    bflag = 1;                                       // benign LDS race (all write 1)
    unsigned long long k = wkey[idx];
    unsigned long long* mb = minE + (b << 16);
    atomicMin(mb + ru, k);
    atomicMin(mb + rv, k);
  }
  __syncthreads();
  if (threadIdx.x == 0 && bflag &&
      __hip_atomic_load(flags + r, __ATOMIC_RELAXED, __HIP_MEMORY_SCOPE_AGENT) == 0)
    __hip_atomic_fetch_or(flags + r, 1, __ATOMIC_RELAXED, __HIP_MEMORY_SCOPE_AGENT);
}

// Round phase 2 (per vertex): mark winners, hook roots, path-compress,
// re-arm minE for the next round.
__global__ void k_hook(const int* __restrict__ root,
                       unsigned long long* __restrict__ minE,
                       int* __restrict__ parent, float* __restrict__ out,
                       const int* __restrict__ flags, int r) {
  if (__hip_atomic_load(flags + r, __ATOMIC_RELAXED,
                        __HIP_MEMORY_SCOPE_AGENT) == 0)
    return;                                          // nothing merged this round
  int idx = blockIdx.x * blockDim.x + threadIdx.x;   // exact B*V grid
  int b = idx >> 16, v = idx & (V - 1);
  int rr = root[idx];
  int np = rr;                                       // compression (non-roots)
  if (rr == v) {
    unsigned long long k = minE[idx];
    if (k != ~0ULL) {
      int e = (int)(k & 0xFFFFFFFFu);
      int eu, ev; edge_uv(e, eu, ev);
      const int* rt = root + (b << 16);
      int ru = rt[eu], rv2 = rt[ev];
      out[b * E + e] = 1.0f;                         // winner (idempotent dup)
      np = (v == ru) ? rv2 : ru;                     // hook to other component
    }
  }
  parent[idx] = np;
  minE[idx] = ~0ULL;                                 // re-arm for next round
}

} // namespace

extern "C" void kernel_launch(void* const* d_in, const int* in_sizes, int n_in,
                              void* d_out, int out_size, void* d_ws, size_t ws_size,
                              hipStream_t stream) {
  const float* x = (const float*)d_in[0];
  float* out = (float*)d_out;

  char* ws = (char*)d_ws;
  size_t off = 0;
  auto alloc = [&](size_t bytes) {
    void* p = (void*)(ws + off);
    off += (bytes + 255) & ~(size_t)255;
    return p;
  };
  int* parent = (int*)alloc((size_t)B * V * sizeof(int));                      // 1 MB
  int* root   = (int*)alloc((size_t)B * V * sizeof(int));                      // 1 MB
  unsigned long long* minE = (unsigned long long*)alloc((size_t)B * V * 8);    // 2 MB
  double* n2  = (double*)alloc((size_t)B * V * sizeof(double));                // 2 MB
  unsigned long long* wkey = (unsigned long long*)alloc((size_t)B * E * 8);    // ~5 MB
  int* flags  = (int*)alloc(ROUNDS * sizeof(int));

  k_norm_init<<<(B * V) / 256, 256, 0, stream>>>(x, n2, parent, minE, flags);
  k_weight<<<(B * E) / 256, 256, 0, stream>>>(x, n2, wkey, out);

  for (int r = 0; r < ROUNDS; ++r) {
    k_edgemin<<<(B * E) / 256, 256, 0, stream>>>(parent, root, wkey, minE, flags, r);
    k_hook   <<<(B * V) / 256, 256, 0, stream>>>(root, minE, parent, out, flags, r);
  }
}